// Round 7
// baseline (682.244 us; speedup 1.0000x reference)
//
#include <hip/hip_runtime.h>
#include <math.h>

// InterAttention B=64, L1=L2=512, D=256 — split-bf16 MFMA, plane layout + DMA staging.
// Pair tensors = two parallel bf16 planes (hi, lo), each E elements; x ~= hi + lo.
// GEMM: Ahi*Bhi + Ahi*Blo + Alo*Bhi on v_mfma_f32_16x16x32_bf16, fp32 accum.
// LDS is FRAGMENT-LINEAR: 8 subtiles x (16 rows x 32 k) in MFMA lane order, so
// frag reads are base + lane*16B (zero bank conflicts) and staging uses
// global_load_lds (wave-uniform base + lane*16 dest, per-lane global src).
//
// ws: 4 slots x E*4 bytes:
//  S0: Wt1/Wt2 corner -> S(fp32) -> RC(planes) -> pool partials
//  S1: T(planes) -> O2t(planes, [l2][l1]) -> WtC1/WtC2 corner
//  S2: H(planes) -> RCMP(fp32)
//  S3: O1(planes) -> C1(planes)

using frag  = __attribute__((ext_vector_type(8))) short;  // 8 x bf16
using f32x4 = __attribute__((ext_vector_type(4))) float;

constexpr long E = 16777216L;   // elements per tensor (65536*256 == 64*512*512)

__device__ __forceinline__ float leaky(float x){ return x > 0.f ? x : 0.01f * x; }

__device__ __forceinline__ unsigned bf16_rne(float f){
    unsigned x = __float_as_uint(f);
    return (x + 0x7fffu + ((x >> 16) & 1u)) >> 16;
}

__device__ __forceinline__ void gload16(const void* g, void* l){
    __builtin_amdgcn_global_load_lds((const __attribute__((address_space(1))) void*)g,
                                     (__attribute__((address_space(3))) void*)l, 16, 0, 0);
}

// AMODE 0: pair planes [M,K] k-contig (DMA). 1: fp32 [M,K] row-split r1/r2 (convert).
// BMODE 0: pair planes [N,K] k-contig (DMA). 1: pair planes [K,N] n-contig (scatter).
// EPI: 0 fp32 plain; 1 pair plain; 2 pair leaky+bias; 3 pair leaky+bias*rowmask; 4 fp32 leaky+bias.
// DUALA: A K-concat (k<K1 from pa, else pa2), AMODE0 only, both PS=PSA.
template<int AMODE, int BMODE, int EPI, int DUALA>
__global__ __launch_bounds__(512, 4)
void gemm_k(const short* __restrict__ pa, const short* __restrict__ pa2,
            const short* __restrict__ pb, const float* __restrict__ bias,
            short* __restrict__ pc,
            const int* __restrict__ mk1, const int* __restrict__ mk2,
            int K, int K1, int lda, int ldb, int ldc,
            long sA, long sB, long sC, long PSA, long PSB, long PSC)
{
    __shared__ __align__(16) short Ah[4096], Al[4096], Bh[4096], Bl[4096];
    const int z = blockIdx.z;
    const int m0 = blockIdx.x * 128, n0 = blockIdx.y * 128;
    const int tid = threadIdx.x, lane = tid & 63, w = tid >> 6;
    const int wr = w >> 2, wc = w & 3;                 // 2x4 waves; wave tile 64x32
    const long aoff = (long)z * sA, boff = (long)z * sB, coff = (long)z * sC;

    f32x4 acc[4][2];
#pragma unroll
    for (int i = 0; i < 4; ++i)
#pragma unroll
        for (int j = 0; j < 2; ++j) acc[i][j] = (f32x4){0.f, 0.f, 0.f, 0.f};

    for (int k0 = 0; k0 < K; k0 += 32) {
        // ---- stage A: wave w owns subtile w (rows m0+w*16..+15, 32 k) ----
        if (AMODE == 0) {
            const short* base = pa + aoff; int kk = k0;
            if (DUALA) { if (k0 >= K1) { base = pa2 + aoff; kk = k0 - K1; } }
            const short* s = base + (long)(m0 + w * 16 + (lane & 15)) * lda + kk + (lane >> 4) * 8;
            gload16(s,       &Ah[w * 512]);
            gload16(s + PSA, &Al[w * 512]);
        } else {
            const int gr = m0 + w * 16 + (lane & 15);
            const float* f = (gr < 32768 ? (const float*)pa + (long)gr * lda
                                         : (const float*)pa2 + (long)(gr - 32768) * lda)
                             + k0 + (lane >> 4) * 8;
            float4 u = *(const float4*)f, v4 = *(const float4*)(f + 4);
            float fv[8] = {u.x, u.y, u.z, u.w, v4.x, v4.y, v4.z, v4.w};
            unsigned hu[8], lu[8];
#pragma unroll
            for (int j = 0; j < 8; ++j) {
                hu[j] = bf16_rne(fv[j]);
                lu[j] = bf16_rne(fv[j] - __uint_as_float(hu[j] << 16));
            }
            uint4 hs = {hu[0] | (hu[1] << 16), hu[2] | (hu[3] << 16), hu[4] | (hu[5] << 16), hu[6] | (hu[7] << 16)};
            uint4 ls = {lu[0] | (lu[1] << 16), lu[2] | (lu[3] << 16), lu[4] | (lu[5] << 16), lu[6] | (lu[7] << 16)};
            *(uint4*)&Ah[w * 512 + lane * 8] = hs;
            *(uint4*)&Al[w * 512 + lane * 8] = ls;
        }
        // ---- stage B ----
        if (BMODE == 0) {
            const short* s = pb + boff + (long)(n0 + w * 16 + (lane & 15)) * ldb + k0 + (lane >> 4) * 8;
            gload16(s,       &Bh[w * 512]);
            gload16(s + PSB, &Bl[w * 512]);
        } else {
            // [K,N] n-contig: thread owns (kg, n): 8 k-strided 2B loads per plane,
            // one contiguous b128 LDS write per plane.
            const int kg = tid >> 7, nn = tid & 127;
            const short* s = pb + boff + (long)(k0 + kg * 8) * ldb + n0 + nn;
            unsigned hh[8], ll[8];
#pragma unroll
            for (int i = 0; i < 8; ++i) {
                hh[i] = (unsigned short)s[(long)i * ldb];
                ll[i] = (unsigned short)s[(long)i * ldb + PSB];
            }
            uint4 hw = {hh[0] | (hh[1] << 16), hh[2] | (hh[3] << 16), hh[4] | (hh[5] << 16), hh[6] | (hh[7] << 16)};
            uint4 lw = {ll[0] | (ll[1] << 16), ll[2] | (ll[3] << 16), ll[4] | (ll[5] << 16), ll[6] | (ll[7] << 16)};
            const int d = (nn >> 4) * 512 + (kg * 16 + (nn & 15)) * 8;
            *(uint4*)&Bh[d] = hw;
            *(uint4*)&Bl[d] = lw;
        }
        __syncthreads();

        // ---- MFMA: frag = subtile base + lane*8 shorts (linear, conflict-free) ----
        frag fah[4], fal[4], fbh[2], fbl[2];
#pragma unroll
        for (int mi = 0; mi < 4; ++mi) {
            const int off = (wr * 4 + mi) * 512 + lane * 8;
            fah[mi] = *(const frag*)&Ah[off];
            fal[mi] = *(const frag*)&Al[off];
        }
#pragma unroll
        for (int ni = 0; ni < 2; ++ni) {
            const int off = (wc * 2 + ni) * 512 + lane * 8;
            fbh[ni] = *(const frag*)&Bh[off];
            fbl[ni] = *(const frag*)&Bl[off];
        }
#pragma unroll
        for (int mi = 0; mi < 4; ++mi)
#pragma unroll
            for (int ni = 0; ni < 2; ++ni) {
                acc[mi][ni] = __builtin_amdgcn_mfma_f32_16x16x32_bf16(fah[mi], fbh[ni], acc[mi][ni], 0, 0, 0);
                acc[mi][ni] = __builtin_amdgcn_mfma_f32_16x16x32_bf16(fah[mi], fbl[ni], acc[mi][ni], 0, 0, 0);
                acc[mi][ni] = __builtin_amdgcn_mfma_f32_16x16x32_bf16(fal[mi], fbh[ni], acc[mi][ni], 0, 0, 0);
            }
        __syncthreads();
    }

    // ---- epilogue ----
    float bvv[2];
    if (EPI == 2 || EPI == 3 || EPI == 4) {
#pragma unroll
        for (int ni = 0; ni < 2; ++ni) bvv[ni] = bias[n0 + wc * 32 + ni * 16 + (lane & 15)];
    }
#pragma unroll
    for (int mi = 0; mi < 4; ++mi)
#pragma unroll
        for (int ni = 0; ni < 2; ++ni) {
            const int col = n0 + wc * 32 + ni * 16 + (lane & 15);
#pragma unroll
            for (int r = 0; r < 4; ++r) {
                const int row = m0 + wr * 64 + mi * 16 + (lane >> 4) * 4 + r;
                float v = acc[mi][ni][r];
                if (EPI == 2 || EPI == 3 || EPI == 4) v = leaky(v + bvv[ni]);
                if (EPI == 3) v *= (float)(row < 32768 ? mk1[row] : mk2[row - 32768]);
                const long off = coff + (long)row * ldc + col;
                if (EPI == 0 || EPI == 4) {
                    ((float*)pc)[off] = v;
                } else {
                    unsigned hu = bf16_rne(v);
                    pc[off]       = (short)hu;
                    pc[off + PSC] = (short)bf16_rne(v - __uint_as_float(hu << 16));
                }
            }
        }
}

// Weight convert+transpose: W [K,256] fp32 -> Wt planes [256,K] (hi, lo at +PS).
__global__ __launch_bounds__(256)
void wconv_k(const float* __restrict__ W, short* __restrict__ T, int Kd, long PS)
{
    const int idx = blockIdx.x * 256 + threadIdx.x;
    const int n = idx & 255, k = idx >> 8;
    const float v = W[idx];
    const unsigned hu = bf16_rne(v);
    T[(long)n * Kd + k]      = (short)hu;
    T[(long)n * Kd + k + PS] = (short)bf16_rne(v - __uint_as_float(hu << 16));
}

// One wave per row of S (fp32); masked softmax over 512 cols -> O1 planes.
__global__ __launch_bounds__(256)
void softmax_row_k(const float* __restrict__ S, const int* __restrict__ m1,
                   const int* __restrict__ m2, short* __restrict__ O)
{
    const int tid = threadIdx.x;
    const int wid = tid >> 6, lane = tid & 63;
    const int gr = blockIdx.x * 4 + wid;
    const int b = gr >> 9, l = gr & 511;
    const float* srow = S + (long)gr * 512;
    short* orow = O + (long)gr * 512;
    const int rowvalid = m1[(long)b * 512 + l];
    const int* m2b = m2 + (long)b * 512;
    const int c8 = lane * 8;
    int4 ma = *(const int4*)(m2b + c8);
    int4 mb_ = *(const int4*)(m2b + c8 + 4);
    float4 va = *(const float4*)(srow + c8);
    float4 vb = *(const float4*)(srow + c8 + 4);
    float v[8] = {va.x, va.y, va.z, va.w, vb.x, vb.y, vb.z, vb.w};
    int mk[8] = {ma.x, ma.y, ma.z, ma.w, mb_.x, mb_.y, mb_.z, mb_.w};
    float mx = -3e38f;
#pragma unroll
    for (int j = 0; j < 8; ++j) if (mk[j]) mx = fmaxf(mx, v[j]);
#pragma unroll
    for (int o = 32; o; o >>= 1) mx = fmaxf(mx, __shfl_xor(mx, o));
    if (!rowvalid || mx < -1e30f) {
        uint4 zz = {0u, 0u, 0u, 0u};
        *(uint4*)&orow[c8] = zz;
        *(uint4*)&orow[c8 + E] = zz;
        return;
    }
    float e[8]; float s = 0.f;
#pragma unroll
    for (int j = 0; j < 8; ++j) { e[j] = mk[j] ? __expf(v[j] - mx) : 0.f; s += e[j]; }
#pragma unroll
    for (int o = 32; o; o >>= 1) s += __shfl_xor(s, o);
    const float inv = 1.f / s;
    unsigned short oh[8], ol[8];
#pragma unroll
    for (int j = 0; j < 8; ++j) {
        float p = e[j] * inv;
        unsigned hu = bf16_rne(p);
        oh[j] = (unsigned short)hu;
        ol[j] = (unsigned short)bf16_rne(p - __uint_as_float(hu << 16));
    }
    uint4 hs = {oh[0] | ((unsigned)oh[1] << 16), oh[2] | ((unsigned)oh[3] << 16),
                oh[4] | ((unsigned)oh[5] << 16), oh[6] | ((unsigned)oh[7] << 16)};
    uint4 ls = {ol[0] | ((unsigned)ol[1] << 16), ol[2] | ((unsigned)ol[3] << 16),
                ol[4] | ((unsigned)ol[5] << 16), ol[6] | ((unsigned)ol[7] << 16)};
    *(uint4*)&orow[c8] = hs;
    *(uint4*)&orow[c8 + E] = ls;
}

// Column softmax, register-resident; writes O2 TRANSPOSED: O2t[b][l2][l1] planes.
__global__ __launch_bounds__(1024)
void softmax_col_k(const float* __restrict__ S, const int* __restrict__ m1,
                   const int* __restrict__ m2, short* __restrict__ O)
{
    __shared__ float red[16][64];
    __shared__ int m1s[512];
    const int b = blockIdx.y;
    const int c0 = blockIdx.x * 64;
    const int tid = threadIdx.x;
    const int c = tid & 63, rq = tid >> 6;          // rq in 0..15
    if (tid < 512) m1s[tid] = m1[(long)b * 512 + tid];
    const int ac = m2[(long)b * 512 + c0 + c];
    const float* Sb = S + (long)b * 262144 + c0 + c;
    __syncthreads();

    float v[32];
#pragma unroll
    for (int g = 0; g < 32; ++g) {
        const int r = g * 16 + rq;
        float val = Sb[(long)r * 512];
        v[g] = m1s[r] ? val : -3e38f;
    }
    float mx = -3e38f;
#pragma unroll
    for (int g = 0; g < 32; ++g) mx = fmaxf(mx, v[g]);
    red[rq][c] = mx;
    __syncthreads();
    float M = -3e38f;
#pragma unroll
    for (int i = 0; i < 16; ++i) M = fmaxf(M, red[i][c]);
    __syncthreads();
    float s = 0.f;
#pragma unroll
    for (int g = 0; g < 32; ++g) {
        float e = (v[g] > -1e30f) ? __expf(v[g] - M) : 0.f;
        v[g] = e;
        s += e;
    }
    red[rq][c] = s;
    __syncthreads();
    s = 0.f;
#pragma unroll
    for (int i = 0; i < 16; ++i) s += red[i][c];
    const float inv = (ac && s > 0.f) ? 1.f / s : 0.f;
    short* oc = O + (long)b * 262144 + (long)(c0 + c) * 512;   // O2t row = l2 col c
#pragma unroll
    for (int g = 0; g < 32; ++g) {
        const int r = g * 16 + rq;
        float p = v[g] * inv;
        unsigned hu = bf16_rne(p);
        oc[r]     = (short)hu;
        oc[r + E] = (short)bf16_rne(p - __uint_as_float(hu << 16));
    }
}

// pool phase 1: partial masked sums over 64-row strips.
__global__ __launch_bounds__(256)
void pool_part_k(const float* __restrict__ RC, const int* __restrict__ m1,
                 const int* __restrict__ m2, float* __restrict__ part)
{
    const int rs = blockIdx.x, b = blockIdx.y, seg = blockIdx.z;
    const int* mb = (seg ? m2 : m1) + (long)b * 512;
    const float* base = RC + ((long)seg * 32768 + (long)b * 512) * 256;
    const int n = threadIdx.x;
    float acc = 0.f;
    for (int l = rs * 64; l < rs * 64 + 64; ++l)
        if (mb[l]) acc += base[(long)l * 256 + n];
    part[(((long)seg * 64 + b) * 8 + rs) * 256 + n] = acc;
}

// pool phase 2: sum 8 partials, divide by mask count.
__global__ __launch_bounds__(256)
void pool_red_k(const float* __restrict__ part, const int* __restrict__ m1,
                const int* __restrict__ m2, float* __restrict__ out)
{
    __shared__ float cr[256];
    const int g = blockIdx.x;                  // seg*64 + b
    const int seg = g >> 6, b = g & 63;
    const int n = threadIdx.x;
    const int* mb = (seg ? m2 : m1) + (long)b * 512;
    float s = 0.f;
#pragma unroll
    for (int i = 0; i < 8; ++i) s += part[((long)g * 8 + i) * 256 + n];
    cr[n] = (float)(mb[n] + mb[n + 256]);
    __syncthreads();
    for (int o = 128; o; o >>= 1) { if (n < o) cr[n] += cr[n + o]; __syncthreads(); }
    out[(long)g * 256 + n] = s / cr[0];
}

extern "C" void kernel_launch(void* const* d_in, const int* in_sizes, int n_in,
                              void* d_out, int out_size, void* d_ws, size_t ws_size,
                              hipStream_t stream)
{
    const float* r1  = (const float*)d_in[0];
    const float* r2  = (const float*)d_in[1];
    const int*   mk1 = (const int*)d_in[2];
    const int*   mk2 = (const int*)d_in[3];
    const float* W1  = (const float*)d_in[4];
    const float* b1  = (const float*)d_in[5];
    const float* W2  = (const float*)d_in[6];
    const float* b2  = (const float*)d_in[7];
    const float* Wc1 = (const float*)d_in[8];
    const float* bc1 = (const float*)d_in[9];
    const float* Wc2 = (const float*)d_in[10];
    const float* bc2 = (const float*)d_in[11];
    float* out = (float*)d_out;

    short* S0s = (short*)d_ws;            // slot stride = 2*E shorts (E*4 bytes)
    short* S1s = S0s + 2 * E;
    short* S2s = S0s + 4 * E;
    short* S3s = S0s + 6 * E;
    short* Wt1  = S0s;                    // [256,256] planes: 2*65536 shorts
    short* Wt2  = S0s + 131072;
    short* WtC1 = S1s;                    // [256,512] planes: 2*131072 shorts
    short* WtC2 = S1s + 262144;
    const long H2 = 8388608;              // h2 / rc2 row offset in plane elements

    // weight transpose+convert (W1, W2 into S0 corner — dead until scores)
    wconv_k<<<256, 256, 0, stream>>>(W1, Wt1, 256, 65536);
    wconv_k<<<256, 256, 0, stream>>>(W2, Wt2, 256, 65536);
    // mlp1: T(S1) = leaky([r1;r2]@W1+b1)
    gemm_k<1,0,2,0><<<dim3(512,2,1), 512, 0, stream>>>(
        (const short*)r1, (const short*)r2, Wt1, b1, S1s, nullptr, nullptr,
        256, 0, 256, 256, 256, 0, 0, 0, 0, 65536, E);
    // mlp2: H(S2) = leaky(T@W2+b2) * rowmask
    gemm_k<0,0,3,0><<<dim3(512,2,1), 512, 0, stream>>>(
        S1s, nullptr, Wt2, b2, S2s, mk1, mk2,
        256, 0, 256, 256, 256, 0, 0, 0, E, 65536, E);
    // scores: S(S0 fp32)[b] = h1[b] @ h2[b]^T
    gemm_k<0,0,0,0><<<dim3(4,4,64), 512, 0, stream>>>(
        S2s, nullptr, S2s + H2, nullptr, S0s, nullptr, nullptr,
        256, 0, 256, 256, 512, 131072, 131072, 262144, E, E, 0);
    // softmaxes: O2t -> S1 (transposed), O1 -> S3
    softmax_col_k<<<dim3(8,64), 1024, 0, stream>>>((const float*)S0s, mk1, mk2, S1s);
    softmax_row_k<<<8192, 256, 0, stream>>>((const float*)S0s, mk1, mk2, S3s);
    // rc1: RC(S0, rows 0..) = O1 @ h2
    gemm_k<0,1,1,0><<<dim3(4,2,64), 512, 0, stream>>>(
        S3s, nullptr, S2s + H2, nullptr, S0s, nullptr, nullptr,
        512, 0, 512, 256, 256, 262144, 131072, 131072, E, E, E);
    // rc2: RC(S0, rows 32768..) = O2t @ h1
    gemm_k<0,1,1,0><<<dim3(4,2,64), 512, 0, stream>>>(
        S1s, nullptr, S2s, nullptr, S0s + H2, nullptr, nullptr,
        512, 0, 512, 256, 256, 262144, 131072, 131072, E, E, E);
    // Wc converts into S1 corner (O2t dead after rc2)
    wconv_k<<<512, 256, 0, stream>>>(Wc1, WtC1, 512, 131072);
    wconv_k<<<256, 256, 0, stream>>>(Wc2, WtC2, 256, 65536);
    // cmp1: C1(S3) = leaky([H|RC]@Wc1+bc1)   (DUALA K-concat)
    gemm_k<0,0,2,1><<<dim3(512,2,1), 512, 0, stream>>>(
        S2s, S0s, WtC1, bc1, S3s, nullptr, nullptr,
        512, 256, 256, 512, 256, 0, 0, 0, E, 131072, E);
    // cmp2: RCMP(S2 fp32) = leaky(C1@Wc2+bc2)
    gemm_k<0,0,4,0><<<dim3(512,2,1), 512, 0, stream>>>(
        S3s, nullptr, WtC2, bc2, S2s, nullptr, nullptr,
        256, 0, 256, 256, 256, 0, 0, 0, E, 65536, 0);
    // masked mean-pool
    pool_part_k<<<dim3(8,64,2), 256, 0, stream>>>((const float*)S2s, mk1, mk2, (float*)S0s);
    pool_red_k<<<128, 256, 0, stream>>>((const float*)S0s, mk1, mk2, out);
}

// Round 8
// 555.158 us; speedup vs baseline: 1.2289x; 1.2289x over previous
//
#include <hip/hip_runtime.h>
#include <math.h>

// InterAttention B=64, L1=L2=512, D=256 — split-bf16 MFMA, plane layout + DMA staging.
// Pair tensors = two parallel bf16 planes (hi, lo), each E elements; x ~= hi + lo.
// GEMM: Ahi*Bhi + Ahi*Blo + Alo*Bhi on v_mfma_f32_16x16x32_bf16, fp32 accum.
// LDS is FRAGMENT-LINEAR: 8 subtiles x (16 rows x 32 k) in MFMA lane order, so
// frag reads are base + lane*16B (zero bank conflicts) and staging uses
// global_load_lds (wave-uniform base + lane*16 dest, per-lane global src).
//
// ws: 4 slots x E*4 bytes:
//  S0: Wt1/Wt2 corner -> S(fp32) -> RC(planes) -> pool partials
//  S1: T(planes) -> O2t(planes, [l2][l1]) -> WtC1/WtC2 corner
//  S2: H(planes) -> RCMP(fp32)
//  S3: O1(planes) -> C1(planes)

using frag  = __attribute__((ext_vector_type(8))) short;  // 8 x bf16
using f32x4 = __attribute__((ext_vector_type(4))) float;

constexpr long E = 16777216L;   // elements per tensor (65536*256 == 64*512*512)

__device__ __forceinline__ float leaky(float x){ return x > 0.f ? x : 0.01f * x; }

__device__ __forceinline__ unsigned bf16_rne(float f){
    unsigned x = __float_as_uint(f);
    return (x + 0x7fffu + ((x >> 16) & 1u)) >> 16;
}

__device__ __forceinline__ void gload16(const void* g, void* l){
    __builtin_amdgcn_global_load_lds((const __attribute__((address_space(1))) void*)g,
                                     (__attribute__((address_space(3))) void*)l, 16, 0, 0);
}

// AMODE 0: pair planes [M,K] k-contig (DMA). 1: fp32 [M,K] row-split r1/r2 (convert).
// BMODE 0: pair planes [N,K] k-contig (DMA). 1: pair planes [K,N] n-contig (scatter).
// EPI: 0 fp32 plain; 1 pair plain; 2 pair leaky+bias; 3 pair leaky+bias*rowmask; 4 fp32 leaky+bias.
// DUALA: A K-concat (k<K1 from pa, else pa2), AMODE0 only, both PS=PSA.
template<int AMODE, int BMODE, int EPI, int DUALA>
__global__ __launch_bounds__(512, 4)
void gemm_k(const short* __restrict__ pa, const short* __restrict__ pa2,
            const short* __restrict__ pb, const float* __restrict__ bias,
            short* __restrict__ pc,
            const int* __restrict__ mk1, const int* __restrict__ mk2,
            int K, int K1, int lda, int ldb, int ldc,
            long sA, long sB, long sC, long PSA, long PSB, long PSC)
{
    __shared__ __align__(16) short Ah[4096], Al[4096], Bh[4096], Bl[4096];
    const int z = blockIdx.z;
    const int m0 = blockIdx.x * 128, n0 = blockIdx.y * 128;
    const int tid = threadIdx.x, lane = tid & 63, w = tid >> 6;
    const int wr = w >> 2, wc = w & 3;                 // 2x4 waves; wave tile 64x32
    const long aoff = (long)z * sA, boff = (long)z * sB, coff = (long)z * sC;

    f32x4 acc[4][2];
#pragma unroll
    for (int i = 0; i < 4; ++i)
#pragma unroll
        for (int j = 0; j < 2; ++j) acc[i][j] = (f32x4){0.f, 0.f, 0.f, 0.f};

    for (int k0 = 0; k0 < K; k0 += 32) {
        // ---- stage A: wave w owns subtile w (rows m0+w*16..+15, 32 k) ----
        if (AMODE == 0) {
            const short* base = pa + aoff; int kk = k0;
            if (DUALA) { if (k0 >= K1) { base = pa2 + aoff; kk = k0 - K1; } }
            const short* s = base + (long)(m0 + w * 16 + (lane & 15)) * lda + kk + (lane >> 4) * 8;
            gload16(s,       &Ah[w * 512]);
            gload16(s + PSA, &Al[w * 512]);
        } else {
            const int gr = m0 + w * 16 + (lane & 15);
            const float* f = (gr < 32768 ? (const float*)pa + (long)gr * lda
                                         : (const float*)pa2 + (long)(gr - 32768) * lda)
                             + k0 + (lane >> 4) * 8;
            float4 u = *(const float4*)f, v4 = *(const float4*)(f + 4);
            float fv[8] = {u.x, u.y, u.z, u.w, v4.x, v4.y, v4.z, v4.w};
            unsigned hu[8], lu[8];
#pragma unroll
            for (int j = 0; j < 8; ++j) {
                hu[j] = bf16_rne(fv[j]);
                lu[j] = bf16_rne(fv[j] - __uint_as_float(hu[j] << 16));
            }
            uint4 hs = {hu[0] | (hu[1] << 16), hu[2] | (hu[3] << 16), hu[4] | (hu[5] << 16), hu[6] | (hu[7] << 16)};
            uint4 ls = {lu[0] | (lu[1] << 16), lu[2] | (lu[3] << 16), lu[4] | (lu[5] << 16), lu[6] | (lu[7] << 16)};
            *(uint4*)&Ah[w * 512 + lane * 8] = hs;
            *(uint4*)&Al[w * 512 + lane * 8] = ls;
        }
        // ---- stage B ----
        if (BMODE == 0) {
            const short* s = pb + boff + (long)(n0 + w * 16 + (lane & 15)) * ldb + k0 + (lane >> 4) * 8;
            gload16(s,       &Bh[w * 512]);
            gload16(s + PSB, &Bl[w * 512]);
        } else {
            // [K,N] n-contig: thread owns (kg, n): 8 k-strided 2B loads per plane,
            // one contiguous b128 LDS write per plane.
            const int kg = tid >> 7, nn = tid & 127;
            const short* s = pb + boff + (long)(k0 + kg * 8) * ldb + n0 + nn;
            unsigned hh[8], ll[8];
#pragma unroll
            for (int i = 0; i < 8; ++i) {
                hh[i] = (unsigned short)s[(long)i * ldb];
                ll[i] = (unsigned short)s[(long)i * ldb + PSB];
            }
            uint4 hw = {hh[0] | (hh[1] << 16), hh[2] | (hh[3] << 16), hh[4] | (hh[5] << 16), hh[6] | (hh[7] << 16)};
            uint4 lw = {ll[0] | (ll[1] << 16), ll[2] | (ll[3] << 16), ll[4] | (ll[5] << 16), ll[6] | (ll[7] << 16)};
            const int d = (nn >> 4) * 512 + (kg * 16 + (nn & 15)) * 8;
            *(uint4*)&Bh[d] = hw;
            *(uint4*)&Bl[d] = lw;
        }
        __syncthreads();

        // ---- MFMA: frag = subtile base + lane*8 shorts (linear, conflict-free) ----
        frag fah[4], fal[4], fbh[2], fbl[2];
#pragma unroll
        for (int mi = 0; mi < 4; ++mi) {
            const int off = (wr * 4 + mi) * 512 + lane * 8;
            fah[mi] = *(const frag*)&Ah[off];
            fal[mi] = *(const frag*)&Al[off];
        }
#pragma unroll
        for (int ni = 0; ni < 2; ++ni) {
            const int off = (wc * 2 + ni) * 512 + lane * 8;
            fbh[ni] = *(const frag*)&Bh[off];
            fbl[ni] = *(const frag*)&Bl[off];
        }
#pragma unroll
        for (int mi = 0; mi < 4; ++mi)
#pragma unroll
            for (int ni = 0; ni < 2; ++ni) {
                acc[mi][ni] = __builtin_amdgcn_mfma_f32_16x16x32_bf16(fah[mi], fbh[ni], acc[mi][ni], 0, 0, 0);
                acc[mi][ni] = __builtin_amdgcn_mfma_f32_16x16x32_bf16(fah[mi], fbl[ni], acc[mi][ni], 0, 0, 0);
                acc[mi][ni] = __builtin_amdgcn_mfma_f32_16x16x32_bf16(fal[mi], fbh[ni], acc[mi][ni], 0, 0, 0);
            }
        __syncthreads();
    }

    // ---- epilogue ----
    float bvv[2];
    if (EPI == 2 || EPI == 3 || EPI == 4) {
#pragma unroll
        for (int ni = 0; ni < 2; ++ni) bvv[ni] = bias[n0 + wc * 32 + ni * 16 + (lane & 15)];
    }
#pragma unroll
    for (int mi = 0; mi < 4; ++mi)
#pragma unroll
        for (int ni = 0; ni < 2; ++ni) {
            const int col = n0 + wc * 32 + ni * 16 + (lane & 15);
#pragma unroll
            for (int r = 0; r < 4; ++r) {
                const int row = m0 + wr * 64 + mi * 16 + (lane >> 4) * 4 + r;
                float v = acc[mi][ni][r];
                if (EPI == 2 || EPI == 3 || EPI == 4) v = leaky(v + bvv[ni]);
                if (EPI == 3) v *= (float)(row < 32768 ? mk1[row] : mk2[row - 32768]);
                const long off = coff + (long)row * ldc + col;
                if (EPI == 0 || EPI == 4) {
                    ((float*)pc)[off] = v;
                } else {
                    unsigned hu = bf16_rne(v);
                    pc[off]       = (short)hu;
                    pc[off + PSC] = (short)bf16_rne(v - __uint_as_float(hu << 16));
                }
            }
        }
}

// Weight convert+transpose: W [K,256] fp32 -> Wt planes [256,K] (hi, lo at +PS).
__global__ __launch_bounds__(256)
void wconv_k(const float* __restrict__ W, short* __restrict__ T, int Kd, long PS)
{
    const int idx = blockIdx.x * 256 + threadIdx.x;
    const int n = idx & 255, k = idx >> 8;
    const float v = W[idx];
    const unsigned hu = bf16_rne(v);
    T[(long)n * Kd + k]      = (short)hu;
    T[(long)n * Kd + k + PS] = (short)bf16_rne(v - __uint_as_float(hu << 16));
}

// One wave per row of S (fp32); masked softmax over 512 cols -> O1 planes.
__global__ __launch_bounds__(256)
void softmax_row_k(const float* __restrict__ S, const int* __restrict__ m1,
                   const int* __restrict__ m2, short* __restrict__ O)
{
    const int tid = threadIdx.x;
    const int wid = tid >> 6, lane = tid & 63;
    const int gr = blockIdx.x * 4 + wid;
    const int b = gr >> 9, l = gr & 511;
    const float* srow = S + (long)gr * 512;
    short* orow = O + (long)gr * 512;
    const int rowvalid = m1[(long)b * 512 + l];
    const int* m2b = m2 + (long)b * 512;
    const int c8 = lane * 8;
    int4 ma = *(const int4*)(m2b + c8);
    int4 mb_ = *(const int4*)(m2b + c8 + 4);
    float4 va = *(const float4*)(srow + c8);
    float4 vb = *(const float4*)(srow + c8 + 4);
    float v[8] = {va.x, va.y, va.z, va.w, vb.x, vb.y, vb.z, vb.w};
    int mk[8] = {ma.x, ma.y, ma.z, ma.w, mb_.x, mb_.y, mb_.z, mb_.w};
    float mx = -3e38f;
#pragma unroll
    for (int j = 0; j < 8; ++j) if (mk[j]) mx = fmaxf(mx, v[j]);
#pragma unroll
    for (int o = 32; o; o >>= 1) mx = fmaxf(mx, __shfl_xor(mx, o));
    if (!rowvalid || mx < -1e30f) {
        uint4 zz = {0u, 0u, 0u, 0u};
        *(uint4*)&orow[c8] = zz;
        *(uint4*)&orow[c8 + E] = zz;
        return;
    }
    float e[8]; float s = 0.f;
#pragma unroll
    for (int j = 0; j < 8; ++j) { e[j] = mk[j] ? __expf(v[j] - mx) : 0.f; s += e[j]; }
#pragma unroll
    for (int o = 32; o; o >>= 1) s += __shfl_xor(s, o);
    const float inv = 1.f / s;
    unsigned short oh[8], ol[8];
#pragma unroll
    for (int j = 0; j < 8; ++j) {
        float p = e[j] * inv;
        unsigned hu = bf16_rne(p);
        oh[j] = (unsigned short)hu;
        ol[j] = (unsigned short)bf16_rne(p - __uint_as_float(hu << 16));
    }
    uint4 hs = {oh[0] | ((unsigned)oh[1] << 16), oh[2] | ((unsigned)oh[3] << 16),
                oh[4] | ((unsigned)oh[5] << 16), oh[6] | ((unsigned)oh[7] << 16)};
    uint4 ls = {ol[0] | ((unsigned)ol[1] << 16), ol[2] | ((unsigned)ol[3] << 16),
                ol[4] | ((unsigned)ol[5] << 16), ol[6] | ((unsigned)ol[7] << 16)};
    *(uint4*)&orow[c8] = hs;
    *(uint4*)&orow[c8 + E] = ls;
}

// Column softmax, register-resident; writes O2 TRANSPOSED via LDS-transpose
// staging so global stores are dense 8B runs (4x128B segments per wave/plane).
__global__ __launch_bounds__(1024)
void softmax_col_k(const float* __restrict__ S, const int* __restrict__ m1,
                   const int* __restrict__ m2, short* __restrict__ O)
{
    __shared__ float red[16][64];
    __shared__ int m1s[512];
    __shared__ unsigned tile[64][65];               // packed (hi<<16|lo), padded
    const int b = blockIdx.y;
    const int c0 = blockIdx.x * 64;
    const int tid = threadIdx.x;
    const int c = tid & 63, rq = tid >> 6;          // rq in 0..15
    if (tid < 512) m1s[tid] = m1[(long)b * 512 + tid];
    const int ac = m2[(long)b * 512 + c0 + c];
    const float* Sb = S + (long)b * 262144 + c0 + c;
    __syncthreads();

    float v[32];
#pragma unroll
    for (int g = 0; g < 32; ++g) {
        const int r = g * 16 + rq;
        float val = Sb[(long)r * 512];
        v[g] = m1s[r] ? val : -3e38f;
    }
    float mx = -3e38f;
#pragma unroll
    for (int g = 0; g < 32; ++g) mx = fmaxf(mx, v[g]);
    red[rq][c] = mx;
    __syncthreads();
    float M = -3e38f;
#pragma unroll
    for (int i = 0; i < 16; ++i) M = fmaxf(M, red[i][c]);
    __syncthreads();
    float s = 0.f;
#pragma unroll
    for (int g = 0; g < 32; ++g) {
        float e = (v[g] > -1e30f) ? __expf(v[g] - M) : 0.f;
        v[g] = e;
        s += e;
    }
    red[rq][c] = s;
    __syncthreads();
    s = 0.f;
#pragma unroll
    for (int i = 0; i < 16; ++i) s += red[i][c];
    const float inv = (ac && s > 0.f) ? 1.f / s : 0.f;

    // transposed write-out: 8 chunks of 64 l1-rows through the LDS tile
    const int oc_ = tid >> 4, or_ = tid & 15;       // write remap
    short* obase = O + (long)b * 262144 + (long)(c0 + oc_) * 512;
    for (int ch = 0; ch < 8; ++ch) {
        __syncthreads();
#pragma unroll
        for (int gg = 0; gg < 4; ++gg) {
            float p = v[ch * 4 + gg] * inv;
            unsigned hu = bf16_rne(p);
            unsigned lu = bf16_rne(p - __uint_as_float(hu << 16));
            tile[c][gg * 16 + rq] = (hu << 16) | lu;
        }
        __syncthreads();
        const unsigned w0 = tile[oc_][or_ * 4 + 0], w1 = tile[oc_][or_ * 4 + 1];
        const unsigned w2 = tile[oc_][or_ * 4 + 2], w3 = tile[oc_][or_ * 4 + 3];
        uint2 ph = { (w0 >> 16) | (w1 & 0xffff0000u), (w2 >> 16) | (w3 & 0xffff0000u) };
        uint2 pl = { (w0 & 0xffffu) | (w1 << 16),     (w2 & 0xffffu) | (w3 << 16) };
        *(uint2*)&obase[ch * 64 + or_ * 4]     = ph;
        *(uint2*)&obase[E + ch * 64 + or_ * 4] = pl;
    }
}

// pool phase 1: partial masked sums over 64-row strips.
__global__ __launch_bounds__(256)
void pool_part_k(const float* __restrict__ RC, const int* __restrict__ m1,
                 const int* __restrict__ m2, float* __restrict__ part)
{
    const int rs = blockIdx.x, b = blockIdx.y, seg = blockIdx.z;
    const int* mb = (seg ? m2 : m1) + (long)b * 512;
    const float* base = RC + ((long)seg * 32768 + (long)b * 512) * 256;
    const int n = threadIdx.x;
    float acc = 0.f;
    for (int l = rs * 64; l < rs * 64 + 64; ++l)
        if (mb[l]) acc += base[(long)l * 256 + n];
    part[(((long)seg * 64 + b) * 8 + rs) * 256 + n] = acc;
}

// pool phase 2: sum 8 partials, divide by mask count.
__global__ __launch_bounds__(256)
void pool_red_k(const float* __restrict__ part, const int* __restrict__ m1,
                const int* __restrict__ m2, float* __restrict__ out)
{
    __shared__ float cr[256];
    const int g = blockIdx.x;                  // seg*64 + b
    const int seg = g >> 6, b = g & 63;
    const int n = threadIdx.x;
    const int* mb = (seg ? m2 : m1) + (long)b * 512;
    float s = 0.f;
#pragma unroll
    for (int i = 0; i < 8; ++i) s += part[((long)g * 8 + i) * 256 + n];
    cr[n] = (float)(mb[n] + mb[n + 256]);
    __syncthreads();
    for (int o = 128; o; o >>= 1) { if (n < o) cr[n] += cr[n + o]; __syncthreads(); }
    out[(long)g * 256 + n] = s / cr[0];
}

extern "C" void kernel_launch(void* const* d_in, const int* in_sizes, int n_in,
                              void* d_out, int out_size, void* d_ws, size_t ws_size,
                              hipStream_t stream)
{
    const float* r1  = (const float*)d_in[0];
    const float* r2  = (const float*)d_in[1];
    const int*   mk1 = (const int*)d_in[2];
    const int*   mk2 = (const int*)d_in[3];
    const float* W1  = (const float*)d_in[4];
    const float* b1  = (const float*)d_in[5];
    const float* W2  = (const float*)d_in[6];
    const float* b2  = (const float*)d_in[7];
    const float* Wc1 = (const float*)d_in[8];
    const float* bc1 = (const float*)d_in[9];
    const float* Wc2 = (const float*)d_in[10];
    const float* bc2 = (const float*)d_in[11];
    float* out = (float*)d_out;

    short* S0s = (short*)d_ws;            // slot stride = 2*E shorts (E*4 bytes)
    short* S1s = S0s + 2 * E;
    short* S2s = S0s + 4 * E;
    short* S3s = S0s + 6 * E;
    short* Wt1  = S0s;                    // [256,256] planes: 2*65536 shorts
    short* Wt2  = S0s + 131072;
    short* WtC1 = S1s;                    // [256,512] planes: 2*131072 shorts
    short* WtC2 = S1s + 262144;
    const long H2 = 8388608;              // h2 / rc2 row offset in plane elements

    // weight transpose+convert (W1, W2 into S0 corner — dead until scores)
    wconv_k<<<256, 256, 0, stream>>>(W1, Wt1, 256, 65536);
    wconv_k<<<256, 256, 0, stream>>>(W2, Wt2, 256, 65536);
    // mlp1: T(S1) = leaky([r1;r2]@W1+b1)
    gemm_k<1,0,2,0><<<dim3(512,2,1), 512, 0, stream>>>(
        (const short*)r1, (const short*)r2, Wt1, b1, S1s, nullptr, nullptr,
        256, 0, 256, 256, 256, 0, 0, 0, 0, 65536, E);
    // mlp2: H(S2) = leaky(T@W2+b2) * rowmask
    gemm_k<0,0,3,0><<<dim3(512,2,1), 512, 0, stream>>>(
        S1s, nullptr, Wt2, b2, S2s, mk1, mk2,
        256, 0, 256, 256, 256, 0, 0, 0, E, 65536, E);
    // scores: S(S0 fp32)[b] = h1[b] @ h2[b]^T
    gemm_k<0,0,0,0><<<dim3(4,4,64), 512, 0, stream>>>(
        S2s, nullptr, S2s + H2, nullptr, S0s, nullptr, nullptr,
        256, 0, 256, 256, 512, 131072, 131072, 262144, E, E, 0);
    // softmaxes: O2t -> S1 (transposed), O1 -> S3
    softmax_col_k<<<dim3(8,64), 1024, 0, stream>>>((const float*)S0s, mk1, mk2, S1s);
    softmax_row_k<<<8192, 256, 0, stream>>>((const float*)S0s, mk1, mk2, S3s);
    // rc1: RC(S0, rows 0..) = O1 @ h2
    gemm_k<0,1,1,0><<<dim3(4,2,64), 512, 0, stream>>>(
        S3s, nullptr, S2s + H2, nullptr, S0s, nullptr, nullptr,
        512, 0, 512, 256, 256, 262144, 131072, 131072, E, E, E);
    // rc2: RC(S0, rows 32768..) = O2t @ h1
    gemm_k<0,1,1,0><<<dim3(4,2,64), 512, 0, stream>>>(
        S1s, nullptr, S2s, nullptr, S0s + H2, nullptr, nullptr,
        512, 0, 512, 256, 256, 262144, 131072, 131072, E, E, E);
    // Wc converts into S1 corner (O2t dead after rc2)
    wconv_k<<<512, 256, 0, stream>>>(Wc1, WtC1, 512, 131072);
    wconv_k<<<256, 256, 0, stream>>>(Wc2, WtC2, 256, 65536);
    // cmp1: C1(S3) = leaky([H|RC]@Wc1+bc1)   (DUALA K-concat)
    gemm_k<0,0,2,1><<<dim3(512,2,1), 512, 0, stream>>>(
        S2s, S0s, WtC1, bc1, S3s, nullptr, nullptr,
        512, 256, 256, 512, 256, 0, 0, 0, E, 131072, E);
    // cmp2: RCMP(S2 fp32) = leaky(C1@Wc2+bc2)
    gemm_k<0,0,4,0><<<dim3(512,2,1), 512, 0, stream>>>(
        S3s, nullptr, WtC2, bc2, S2s, nullptr, nullptr,
        256, 0, 256, 256, 256, 0, 0, 0, E, 65536, 0);
    // masked mean-pool
    pool_part_k<<<dim3(8,64,2), 256, 0, stream>>>((const float*)S2s, mk1, mk2, (float*)S0s);
    pool_red_k<<<128, 256, 0, stream>>>((const float*)S0s, mk1, mk2, out);
}

// Round 11
// 540.948 us; speedup vs baseline: 1.2612x; 1.0263x over previous
//
#include <hip/hip_runtime.h>
#include <math.h>

// InterAttention B=64, L1=L2=512, D=256 — split-bf16 MFMA, plane layout + DMA staging
// + double-buffered 2-phase K-loop (prefetch k+1 overlaps MFMA of k; 1 barrier/step).
// Pair tensors = two parallel bf16 planes (hi, lo), each E elements; x ~= hi + lo.
// GEMM: Ahi*Bhi + Ahi*Blo + Alo*Bhi on v_mfma_f32_16x16x32_bf16, fp32 accum.
// LDS fragment-linear: 8 subtiles x (16 rows x 32 k) in MFMA lane order.
//
// ws: 4 slots x E*4 bytes:
//  S0: Wt1/Wt2 corner -> S(fp32) -> RC(planes) -> pool partials
//  S1: T(planes) -> O2t(planes, [l2][l1]) -> WtC1/WtC2 corner
//  S2: H(planes) -> RCMP(fp32)
//  S3: O1(planes) -> C1(planes)

using frag  = __attribute__((ext_vector_type(8))) short;  // 8 x bf16
using f32x4 = __attribute__((ext_vector_type(4))) float;

constexpr long E = 16777216L;   // elements per tensor (65536*256 == 64*512*512)

__device__ __forceinline__ float leaky(float x){ return x > 0.f ? x : 0.01f * x; }

__device__ __forceinline__ unsigned bf16_rne(float f){
    unsigned x = __float_as_uint(f);
    return (x + 0x7fffu + ((x >> 16) & 1u)) >> 16;
}

__device__ __forceinline__ void gload16(const void* g, void* l){
    __builtin_amdgcn_global_load_lds((const __attribute__((address_space(1))) void*)g,
                                     (__attribute__((address_space(3))) void*)l, 16, 0, 0);
}

// AMODE 0: pair planes [M,K] k-contig (DMA). 1: fp32 [M,K] row-split r1/r2 (convert).
// BMODE 0: pair planes [N,K] k-contig (DMA). 1: pair planes [K,N] n-contig (scatter).
// EPI: 0 fp32 plain; 1 pair plain; 2 pair leaky+bias; 3 pair leaky+bias*rowmask; 4 fp32 leaky+bias.
// DUALA: A K-concat (k<K1 from pa, else pa2), AMODE0 only, both PS=PSA.
template<int AMODE, int BMODE, int EPI, int DUALA>
__global__ __launch_bounds__(512, 4)
void gemm_k(const short* __restrict__ pa, const short* __restrict__ pa2,
            const short* __restrict__ pb, const float* __restrict__ bias,
            short* __restrict__ pc,
            const int* __restrict__ mk1, const int* __restrict__ mk2,
            int K, int K1, int lda, int ldb, int ldc,
            long sA, long sB, long sC, long PSA, long PSB, long PSC)
{
    __shared__ __align__(16) short Ah[2][4096], Al[2][4096], Bh[2][4096], Bl[2][4096];
    const int z = blockIdx.z;
    const int m0 = blockIdx.x * 128, n0 = blockIdx.y * 128;
    const int tid = threadIdx.x, lane = tid & 63, w = tid >> 6;
    const int wr = w >> 2, wc = w & 3;                 // 2x4 waves; wave tile 64x32
    const long aoff = (long)z * sA, boff = (long)z * sB, coff = (long)z * sC;

    const auto stage = [&](int buf, int k0) {
        // ---- stage A: wave w owns subtile w (rows m0+w*16..+15, 32 k) ----
        if (AMODE == 0) {
            const short* base = pa + aoff; int kk = k0;
            if (DUALA) { if (k0 >= K1) { base = pa2 + aoff; kk = k0 - K1; } }
            const short* s = base + (long)(m0 + w * 16 + (lane & 15)) * lda + kk + (lane >> 4) * 8;
            gload16(s,       &Ah[buf][w * 512]);
            gload16(s + PSA, &Al[buf][w * 512]);
        } else {
            const int gr = m0 + w * 16 + (lane & 15);
            const float* f = (gr < 32768 ? (const float*)pa + (long)gr * lda
                                         : (const float*)pa2 + (long)(gr - 32768) * lda)
                             + k0 + (lane >> 4) * 8;
            float4 u = *(const float4*)f, v4 = *(const float4*)(f + 4);
            float fv[8] = {u.x, u.y, u.z, u.w, v4.x, v4.y, v4.z, v4.w};
            unsigned hu[8], lu[8];
#pragma unroll
            for (int j = 0; j < 8; ++j) {
                hu[j] = bf16_rne(fv[j]);
                lu[j] = bf16_rne(fv[j] - __uint_as_float(hu[j] << 16));
            }
            uint4 hs = {hu[0] | (hu[1] << 16), hu[2] | (hu[3] << 16), hu[4] | (hu[5] << 16), hu[6] | (hu[7] << 16)};
            uint4 ls = {lu[0] | (lu[1] << 16), lu[2] | (lu[3] << 16), lu[4] | (lu[5] << 16), lu[6] | (lu[7] << 16)};
            *(uint4*)&Ah[buf][w * 512 + lane * 8] = hs;
            *(uint4*)&Al[buf][w * 512 + lane * 8] = ls;
        }
        // ---- stage B ----
        if (BMODE == 0) {
            const short* s = pb + boff + (long)(n0 + w * 16 + (lane & 15)) * ldb + k0 + (lane >> 4) * 8;
            gload16(s,       &Bh[buf][w * 512]);
            gload16(s + PSB, &Bl[buf][w * 512]);
        } else {
            // [K,N] n-contig: thread owns (kg, n): 8 k-strided 2B loads per plane,
            // one contiguous b128 LDS write per plane.
            const int kg = tid >> 7, nn = tid & 127;
            const short* s = pb + boff + (long)(k0 + kg * 8) * ldb + n0 + nn;
            unsigned hh[8], ll[8];
#pragma unroll
            for (int i = 0; i < 8; ++i) {
                hh[i] = (unsigned short)s[(long)i * ldb];
                ll[i] = (unsigned short)s[(long)i * ldb + PSB];
            }
            uint4 hw = {hh[0] | (hh[1] << 16), hh[2] | (hh[3] << 16), hh[4] | (hh[5] << 16), hh[6] | (hh[7] << 16)};
            uint4 lw = {ll[0] | (ll[1] << 16), ll[2] | (ll[3] << 16), ll[4] | (ll[5] << 16), ll[6] | (ll[7] << 16)};
            const int d = (nn >> 4) * 512 + (kg * 16 + (nn & 15)) * 8;
            *(uint4*)&Bh[buf][d] = hw;
            *(uint4*)&Bl[buf][d] = lw;
        }
    };

    f32x4 acc[4][2];
#pragma unroll
    for (int i = 0; i < 4; ++i)
#pragma unroll
        for (int j = 0; j < 2; ++j) acc[i][j] = (f32x4){0.f, 0.f, 0.f, 0.f};

    // prologue: fill buffer 0
    stage(0, 0);
    __syncthreads();

    int cur = 0;
    for (int k0 = 0; k0 < K; k0 += 32) {
        // prefetch next tile into the idle buffer (drained by the barrier below,
        // AFTER this tile's ds_read+MFMA — the latency hides under compute)
        if (k0 + 32 < K) stage(cur ^ 1, k0 + 32);

        // ---- MFMA on buf[cur]: frag = subtile base + lane*8 shorts ----
        frag fah[4], fal[4], fbh[2], fbl[2];
#pragma unroll
        for (int mi = 0; mi < 4; ++mi) {
            const int off = (wr * 4 + mi) * 512 + lane * 8;
            fah[mi] = *(const frag*)&Ah[cur][off];
            fal[mi] = *(const frag*)&Al[cur][off];
        }
#pragma unroll
        for (int ni = 0; ni < 2; ++ni) {
            const int off = (wc * 2 + ni) * 512 + lane * 8;
            fbh[ni] = *(const frag*)&Bh[cur][off];
            fbl[ni] = *(const frag*)&Bl[cur][off];
        }
#pragma unroll
        for (int mi = 0; mi < 4; ++mi)
#pragma unroll
            for (int ni = 0; ni < 2; ++ni) {
                acc[mi][ni] = __builtin_amdgcn_mfma_f32_16x16x32_bf16(fah[mi], fbh[ni], acc[mi][ni], 0, 0, 0);
                acc[mi][ni] = __builtin_amdgcn_mfma_f32_16x16x32_bf16(fah[mi], fbl[ni], acc[mi][ni], 0, 0, 0);
                acc[mi][ni] = __builtin_amdgcn_mfma_f32_16x16x32_bf16(fal[mi], fbh[ni], acc[mi][ni], 0, 0, 0);
            }
        __syncthreads();   // drains prefetch (vmcnt 0) + guards buf[cur] reuse
        cur ^= 1;
    }

    // ---- epilogue ----
    float bvv[2];
    if (EPI == 2 || EPI == 3 || EPI == 4) {
#pragma unroll
        for (int ni = 0; ni < 2; ++ni) bvv[ni] = bias[n0 + wc * 32 + ni * 16 + (lane & 15)];
    }
#pragma unroll
    for (int mi = 0; mi < 4; ++mi)
#pragma unroll
        for (int ni = 0; ni < 2; ++ni) {
            const int col = n0 + wc * 32 + ni * 16 + (lane & 15);
#pragma unroll
            for (int r = 0; r < 4; ++r) {
                const int row = m0 + wr * 64 + mi * 16 + (lane >> 4) * 4 + r;
                float v = acc[mi][ni][r];
                if (EPI == 2 || EPI == 3 || EPI == 4) v = leaky(v + bvv[ni]);
                if (EPI == 3) v *= (float)(row < 32768 ? mk1[row] : mk2[row - 32768]);
                const long off = coff + (long)row * ldc + col;
                if (EPI == 0 || EPI == 4) {
                    ((float*)pc)[off] = v;
                } else {
                    unsigned hu = bf16_rne(v);
                    pc[off]       = (short)hu;
                    pc[off + PSC] = (short)bf16_rne(v - __uint_as_float(hu << 16));
                }
            }
        }
}

// Weight convert+transpose: W [K,256] fp32 -> Wt planes [256,K] (hi, lo at +PS).
__global__ __launch_bounds__(256)
void wconv_k(const float* __restrict__ W, short* __restrict__ T, int Kd, long PS)
{
    const int idx = blockIdx.x * 256 + threadIdx.x;
    const int n = idx & 255, k = idx >> 8;
    const float v = W[idx];
    const unsigned hu = bf16_rne(v);
    T[(long)n * Kd + k]      = (short)hu;
    T[(long)n * Kd + k + PS] = (short)bf16_rne(v - __uint_as_float(hu << 16));
}

// One wave per row of S (fp32); masked softmax over 512 cols -> O1 planes.
__global__ __launch_bounds__(256)
void softmax_row_k(const float* __restrict__ S, const int* __restrict__ m1,
                   const int* __restrict__ m2, short* __restrict__ O)
{
    const int tid = threadIdx.x;
    const int wid = tid >> 6, lane = tid & 63;
    const int gr = blockIdx.x * 4 + wid;
    const int b = gr >> 9, l = gr & 511;
    const float* srow = S + (long)gr * 512;
    short* orow = O + (long)gr * 512;
    const int rowvalid = m1[(long)b * 512 + l];
    const int* m2b = m2 + (long)b * 512;
    const int c8 = lane * 8;
    int4 ma = *(const int4*)(m2b + c8);
    int4 mb_ = *(const int4*)(m2b + c8 + 4);
    float4 va = *(const float4*)(srow + c8);
    float4 vb = *(const float4*)(srow + c8 + 4);
    float v[8] = {va.x, va.y, va.z, va.w, vb.x, vb.y, vb.z, vb.w};
    int mk[8] = {ma.x, ma.y, ma.z, ma.w, mb_.x, mb_.y, mb_.z, mb_.w};
    float mx = -3e38f;
#pragma unroll
    for (int j = 0; j < 8; ++j) if (mk[j]) mx = fmaxf(mx, v[j]);
#pragma unroll
    for (int o = 32; o; o >>= 1) mx = fmaxf(mx, __shfl_xor(mx, o));
    if (!rowvalid || mx < -1e30f) {
        uint4 zz = {0u, 0u, 0u, 0u};
        *(uint4*)&orow[c8] = zz;
        *(uint4*)&orow[c8 + E] = zz;
        return;
    }
    float e[8]; float s = 0.f;
#pragma unroll
    for (int j = 0; j < 8; ++j) { e[j] = mk[j] ? __expf(v[j] - mx) : 0.f; s += e[j]; }
#pragma unroll
    for (int o = 32; o; o >>= 1) s += __shfl_xor(s, o);
    const float inv = 1.f / s;
    unsigned short oh[8], ol[8];
#pragma unroll
    for (int j = 0; j < 8; ++j) {
        float p = e[j] * inv;
        unsigned hu = bf16_rne(p);
        oh[j] = (unsigned short)hu;
        ol[j] = (unsigned short)bf16_rne(p - __uint_as_float(hu << 16));
    }
    uint4 hs = {oh[0] | ((unsigned)oh[1] << 16), oh[2] | ((unsigned)oh[3] << 16),
                oh[4] | ((unsigned)oh[5] << 16), oh[6] | ((unsigned)oh[7] << 16)};
    uint4 ls = {ol[0] | ((unsigned)ol[1] << 16), ol[2] | ((unsigned)ol[3] << 16),
                ol[4] | ((unsigned)ol[5] << 16), ol[6] | ((unsigned)ol[7] << 16)};
    *(uint4*)&orow[c8] = hs;
    *(uint4*)&orow[c8 + E] = ls;
}

// Column softmax, register-resident; writes O2 TRANSPOSED via LDS-transpose
// staging so global stores are dense 8B runs (4x128B segments per wave/plane).
__global__ __launch_bounds__(1024)
void softmax_col_k(const float* __restrict__ S, const int* __restrict__ m1,
                   const int* __restrict__ m2, short* __restrict__ O)
{
    __shared__ float red[16][64];
    __shared__ int m1s[512];
    __shared__ unsigned tile[64][65];               // packed (hi<<16|lo), padded
    const int b = blockIdx.y;
    const int c0 = blockIdx.x * 64;
    const int tid = threadIdx.x;
    const int c = tid & 63, rq = tid >> 6;          // rq in 0..15
    if (tid < 512) m1s[tid] = m1[(long)b * 512 + tid];
    const int ac = m2[(long)b * 512 + c0 + c];
    const float* Sb = S + (long)b * 262144 + c0 + c;
    __syncthreads();

    float v[32];
#pragma unroll
    for (int g = 0; g < 32; ++g) {
        const int r = g * 16 + rq;
        float val = Sb[(long)r * 512];
        v[g] = m1s[r] ? val : -3e38f;
    }
    float mx = -3e38f;
#pragma unroll
    for (int g = 0; g < 32; ++g) mx = fmaxf(mx, v[g]);
    red[rq][c] = mx;
    __syncthreads();
    float M = -3e38f;
#pragma unroll
    for (int i = 0; i < 16; ++i) M = fmaxf(M, red[i][c]);
    __syncthreads();
    float s = 0.f;
#pragma unroll
    for (int g = 0; g < 32; ++g) {
        float e = (v[g] > -1e30f) ? __expf(v[g] - M) : 0.f;
        v[g] = e;
        s += e;
    }
    red[rq][c] = s;
    __syncthreads();
    s = 0.f;
#pragma unroll
    for (int i = 0; i < 16; ++i) s += red[i][c];
    const float inv = (ac && s > 0.f) ? 1.f / s : 0.f;

    // transposed write-out: 8 chunks of 64 l1-rows through the LDS tile
    const int oc_ = tid >> 4, or_ = tid & 15;       // write remap
    short* obase = O + (long)b * 262144 + (long)(c0 + oc_) * 512;
    for (int ch = 0; ch < 8; ++ch) {
        __syncthreads();
#pragma unroll
        for (int gg = 0; gg < 4; ++gg) {
            float p = v[ch * 4 + gg] * inv;
            unsigned hu = bf16_rne(p);
            unsigned lu = bf16_rne(p - __uint_as_float(hu << 16));
            tile[c][gg * 16 + rq] = (hu << 16) | lu;
        }
        __syncthreads();
        const unsigned w0 = tile[oc_][or_ * 4 + 0], w1 = tile[oc_][or_ * 4 + 1];
        const unsigned w2 = tile[oc_][or_ * 4 + 2], w3 = tile[oc_][or_ * 4 + 3];
        uint2 ph = { (w0 >> 16) | (w1 & 0xffff0000u), (w2 >> 16) | (w3 & 0xffff0000u) };
        uint2 pl = { (w0 & 0xffffu) | (w1 << 16),     (w2 & 0xffffu) | (w3 << 16) };
        *(uint2*)&obase[ch * 64 + or_ * 4]     = ph;
        *(uint2*)&obase[E + ch * 64 + or_ * 4] = pl;
    }
}

// pool phase 1: partial masked sums over 64-row strips.
__global__ __launch_bounds__(256)
void pool_part_k(const float* __restrict__ RC, const int* __restrict__ m1,
                 const int* __restrict__ m2, float* __restrict__ part)
{
    const int rs = blockIdx.x, b = blockIdx.y, seg = blockIdx.z;
    const int* mb = (seg ? m2 : m1) + (long)b * 512;
    const float* base = RC + ((long)seg * 32768 + (long)b * 512) * 256;
    const int n = threadIdx.x;
    float acc = 0.f;
    for (int l = rs * 64; l < rs * 64 + 64; ++l)
        if (mb[l]) acc += base[(long)l * 256 + n];
    part[(((long)seg * 64 + b) * 8 + rs) * 256 + n] = acc;
}

// pool phase 2: sum 8 partials, divide by mask count.
__global__ __launch_bounds__(256)
void pool_red_k(const float* __restrict__ part, const int* __restrict__ m1,
                const int* __restrict__ m2, float* __restrict__ out)
{
    __shared__ float cr[256];
    const int g = blockIdx.x;                  // seg*64 + b
    const int seg = g >> 6, b = g & 63;
    const int n = threadIdx.x;
    const int* mb = (seg ? m2 : m1) + (long)b * 512;
    float s = 0.f;
#pragma unroll
    for (int i = 0; i < 8; ++i) s += part[((long)g * 8 + i) * 256 + n];
    cr[n] = (float)(mb[n] + mb[n + 256]);
    __syncthreads();
    for (int o = 128; o; o >>= 1) { if (n < o) cr[n] += cr[n + o]; __syncthreads(); }
    out[(long)g * 256 + n] = s / cr[0];
}

extern "C" void kernel_launch(void* const* d_in, const int* in_sizes, int n_in,
                              void* d_out, int out_size, void* d_ws, size_t ws_size,
                              hipStream_t stream)
{
    const float* r1  = (const float*)d_in[0];
    const float* r2  = (const float*)d_in[1];
    const int*   mk1 = (const int*)d_in[2];
    const int*   mk2 = (const int*)d_in[3];
    const float* W1  = (const float*)d_in[4];
    const float* b1  = (const float*)d_in[5];
    const float* W2  = (const float*)d_in[6];
    const float* b2  = (const float*)d_in[7];
    const float* Wc1 = (const float*)d_in[8];
    const float* bc1 = (const float*)d_in[9];
    const float* Wc2 = (const float*)d_in[10];
    const float* bc2 = (const float*)d_in[11];
    float* out = (float*)d_out;

    short* S0s = (short*)d_ws;            // slot stride = 2*E shorts (E*4 bytes)
    short* S1s = S0s + 2 * E;
    short* S2s = S0s + 4 * E;
    short* S3s = S0s + 6 * E;
    short* Wt1  = S0s;                    // [256,256] planes: 2*65536 shorts
    short* Wt2  = S0s + 131072;
    short* WtC1 = S1s;                    // [256,512] planes: 2*131072 shorts
    short* WtC2 = S1s + 262144;
    const long H2 = 8388608;              // h2 / rc2 row offset in plane elements

    // weight transpose+convert (W1, W2 into S0 corner — dead until scores)
    wconv_k<<<256, 256, 0, stream>>>(W1, Wt1, 256, 65536);
    wconv_k<<<256, 256, 0, stream>>>(W2, Wt2, 256, 65536);
    // mlp1: T(S1) = leaky([r1;r2]@W1+b1)
    gemm_k<1,0,2,0><<<dim3(512,2,1), 512, 0, stream>>>(
        (const short*)r1, (const short*)r2, Wt1, b1, S1s, nullptr, nullptr,
        256, 0, 256, 256, 256, 0, 0, 0, 0, 65536, E);
    // mlp2: H(S2) = leaky(T@W2+b2) * rowmask
    gemm_k<0,0,3,0><<<dim3(512,2,1), 512, 0, stream>>>(
        S1s, nullptr, Wt2, b2, S2s, mk1, mk2,
        256, 0, 256, 256, 256, 0, 0, 0, E, 65536, E);
    // scores: S(S0 fp32)[b] = h1[b] @ h2[b]^T
    gemm_k<0,0,0,0><<<dim3(4,4,64), 512, 0, stream>>>(
        S2s, nullptr, S2s + H2, nullptr, S0s, nullptr, nullptr,
        256, 0, 256, 256, 512, 131072, 131072, 262144, E, E, 0);
    // softmaxes: O2t -> S1 (transposed), O1 -> S3
    softmax_col_k<<<dim3(8,64), 1024, 0, stream>>>((const float*)S0s, mk1, mk2, S1s);
    softmax_row_k<<<8192, 256, 0, stream>>>((const float*)S0s, mk1, mk2, S3s);
    // rc1: RC(S0, rows 0..) = O1 @ h2
    gemm_k<0,1,1,0><<<dim3(4,2,64), 512, 0, stream>>>(
        S3s, nullptr, S2s + H2, nullptr, S0s, nullptr, nullptr,
        512, 0, 512, 256, 256, 262144, 131072, 131072, E, E, E);
    // rc2: RC(S0, rows 32768..) = O2t @ h1
    gemm_k<0,1,1,0><<<dim3(4,2,64), 512, 0, stream>>>(
        S1s, nullptr, S2s, nullptr, S0s + H2, nullptr, nullptr,
        512, 0, 512, 256, 256, 262144, 131072, 131072, E, E, E);
    // Wc converts into S1 corner (O2t dead after rc2)
    wconv_k<<<512, 256, 0, stream>>>(Wc1, WtC1, 512, 131072);
    wconv_k<<<256, 256, 0, stream>>>(Wc2, WtC2, 256, 65536);
    // cmp1: C1(S3) = leaky([H|RC]@Wc1+bc1)   (DUALA K-concat)
    gemm_k<0,0,2,1><<<dim3(512,2,1), 512, 0, stream>>>(
        S2s, S0s, WtC1, bc1, S3s, nullptr, nullptr,
        512, 256, 256, 512, 256, 0, 0, 0, E, 131072, E);
    // cmp2: RCMP(S2 fp32) = leaky(C1@Wc2+bc2)
    gemm_k<0,0,4,0><<<dim3(512,2,1), 512, 0, stream>>>(
        S3s, nullptr, WtC2, bc2, S2s, nullptr, nullptr,
        256, 0, 256, 256, 256, 0, 0, 0, E, 65536, 0);
    // masked mean-pool
    pool_part_k<<<dim3(8,64,2), 256, 0, stream>>>((const float*)S2s, mk1, mk2, (float*)S0s);
    pool_red_k<<<128, 256, 0, stream>>>((const float*)S0s, mk1, mk2, out);
}